// Round 5
// baseline (324.029 us; speedup 1.0000x reference)
//
#include <hip/hip_runtime.h>
#include <math.h>

// Algebraic collapse: out depends on h = X@We + be only through h@Wc and h@Wf.
//   logits[:, 0:20]  = X @ (We@Wc) + (be@Wc + bc)
//   logits[:, 20:40] = X @ (We@Wf) + (be@Wf + bf)
// K0: zero Weff, fold bias2 = [be@Wc + bc | be@Wf + bf]
// K1: Weff = We @ [Wc|Wf]   (panel_gemm<2,false>, 4-way block-K atomic split)
// K2: out  = epilogue(X @ Weff + bias2)   (panel_gemm<8,true>)
//
// Round-5: round 4 hit the unified-register-file cliff: launch_bounds(512,4)
// caps VGPR+AGPR at 128/wave combined; demand ~130 -> allocator split 64+64
// and shuttled the accumulator through v_accvgpr_read/write (VALUBusy 28% =
// ~3.5x the fma work) plus 7 MB scratch. Fix: move to the 256-reg tier and
// buy the latency tolerance back with explicit pipelining instead of TLP:
//  - __launch_bounds__(512,2): 8 waves/CU, 256 regs/wave, demand ~150 fits
//  - double-buffered B panel (2 x 41.3 KB): next super's B global loads
//    issued BEFORE compute, ds_writes AFTER compute (T14 split) -> staging
//    latency hidden under ~700 cyc of fma work
//  - X depth-2 pipeline: step t's regs refilled for step t+2 right after
//    last use -> no per-step global-latency stall; in-order vmcnt retirement
//    means X waits leave staging loads in flight (no forced drains)
//  - same 4cg x 2rg, 8 rows/thread tiling (each ds_read_b128 feeds 16
//    pk_fma; aggregate LDS ~13 us < HBM floor 21 us)
// Reduce tree + epilogue copied verbatim from round 4 (passed, absmax 0.0).

typedef float v2f __attribute__((ext_vector_type(2)));
typedef float v4f __attribute__((ext_vector_type(4)));

#define KD    2048
#define NCLS  20
#define SMARG 0.31f

// ws layout (floats): Weff[2048*40] row-major, then bias2[40]
#define WEFF_OFF 0
#define BIAS_OFF 81920

#define PROW  516                   // paired panel row stride (512+4), 16B-aligned
#define PANEL_FLOATS (20 * PROW)    // 10320 floats = 41280 B per buffer
#define HROW  164                   // Hacc row: 40 cols x 4 partials + 4 pad

static __device__ __forceinline__ v2f fma2(v2f a, v2f b, v2f c) {
#if __has_builtin(__builtin_elementwise_fma)
    return __builtin_elementwise_fma(a, b, c);   // -> v_pk_fma_f32
#else
    v2f r; r[0] = fmaf(a[0], b[0], c[0]); r[1] = fmaf(a[1], b[1], c[1]); return r;
#endif
}

// ---------------- K0: zero Weff, fold bias2 --------------------------------
__global__ __launch_bounds__(256)
void k0_prep(const float* __restrict__ Wc, const float* __restrict__ bc,
             const float* __restrict__ Wf, const float* __restrict__ bf,
             const float* __restrict__ be, float* __restrict__ ws)
{
    const int b = blockIdx.x;
    const int t = threadIdx.x;
    if (b < 80) {                                   // zero Weff: 80*256*4 = 81920
        v4f z = {0.f, 0.f, 0.f, 0.f};
        *(v4f*)&ws[WEFF_OFF + 4 * (b * 256 + t)] = z;
    } else {                                        // bias2[col], col = b-80
        const int col = b - 80;
        const float* Wp = (col < NCLS) ? Wc : Wf;
        const int cc = (col < NCLS) ? col : col - NCLS;
        float p = 0.f;
        for (int n = t; n < KD; n += 256)
            p = fmaf(be[n], Wp[n * NCLS + cc], p);
        __shared__ float red[256];
        red[t] = p;
        __syncthreads();
        for (int s = 128; s > 0; s >>= 1) {
            if (t < s) red[t] += red[t + s];
            __syncthreads();
        }
        if (t == 0)
            ws[BIAS_OFF + col] = red[0] + ((col < NCLS) ? bc[cc] : bf[cc]);
    }
}

// ---------------- panel GEMM: C[M,40] (+=) A[M,2048] @ B[2048,40] ----------
// Block: 512 thr = 8 waves = 4 col-groups(10 cols) x 2 row-groups(8 rows).
// Lanes span k. X read directly from global, coalesced, touched once,
// pipelined depth 2. B staged per 256-k super into a double-buffered paired
// LDS panel [cj][2k] (stride 516), read as contiguous ds_read_b128.
// acc2[8][5] v2f -> v_pk_fma_f32. End: recursive-halving shfl reduce
// (static GEPs only) -> LDS Hacc -> 16 row-lanes finalize.
template<int NSUP, bool FUSED>
__global__ __launch_bounds__(512, 2)
void panel_gemm(const float* __restrict__ A,
                const float* __restrict__ B0,
                const float* __restrict__ B1,
                float* __restrict__ Cacc,
                const float* __restrict__ bias2,
                float* __restrict__ outp)
{
    __shared__ __align__(16) float smem[2 * PANEL_FLOATS];
    const int tid  = threadIdx.x;
    const int lane = tid & 63;
    const int w    = tid >> 6;          // wave 0..7
    const int cg   = w & 3;             // col-group: cols [cg*10, cg*10+10)
    const int rg   = w >> 2;            // row-group: rows [rg*8, rg*8+8)

    int m0, kbase;
    if (FUSED) { m0 = blockIdx.x * 16;              kbase = 0; }
    else       { m0 = (int)(blockIdx.x >> 2) * 16;  kbase = (int)(blockIdx.x & 3) * 512; }

    const float* Arow = A + (size_t)(m0 + rg * 8) * KD + kbase + 2 * lane;

    // ---- staging helpers (B global -> regs -> LDS) -------------------------
#define STAGE_LOAD(sv, kb)                                                     \
    {                                                                          \
        _Pragma("unroll")                                                      \
        for (int it = 0; it < 10; ++it) {                                      \
            const int pi = tid + it * 512;          /* < 5120 pairs */         \
            const int k = pi / 20, cj = pi % 20;                               \
            const float* bp;                                                   \
            unsigned soff;                                                     \
            if (FUSED)        { bp = B0; soff = (unsigned)((kb) + k) * 40 + 2 * cj; } \
            else if (cj < 10) { bp = B0; soff = (unsigned)((kb) + k) * 20 + 2 * cj; } \
            else              { bp = B1; soff = (unsigned)((kb) + k) * 20 + 2 * (cj - 10); } \
            sv[it] = *(const v2f*)(bp + soff);                                 \
        }                                                                      \
    }
#define STAGE_WRITE(sv, dst)                                                   \
    {                                                                          \
        _Pragma("unroll")                                                      \
        for (int it = 0; it < 10; ++it) {                                      \
            const int pi = tid + it * 512;                                     \
            const int k = pi / 20, cj = pi % 20;                               \
            *(v2f*)((dst) + cj * PROW + 2 * k) = sv[it];                       \
        }                                                                      \
    }
#define LOAD_X(xr, step)                                                       \
    {                                                                          \
        _Pragma("unroll")                                                      \
        for (int r = 0; r < 8; ++r)                                            \
            xr[r] = *(const v2f*)(Arow + r * KD + (step) * 128);               \
    }
#define COMPUTE(xr, base)                                                      \
    {                                                                          \
        const float* pb = (base) + cg * (5 * PROW) + 4 * lane;                 \
        _Pragma("unroll")                                                      \
        for (int j2 = 0; j2 < 5; ++j2) {                                       \
            v4f bv  = *(const v4f*)(pb + j2 * PROW);   /* contiguous b128 */   \
            v2f blo = {bv[0], bv[1]}, bhi = {bv[2], bv[3]};                    \
            _Pragma("unroll")                                                  \
            for (int r = 0; r < 8; ++r) {                                      \
                v2f x0 = {xr[r][0], xr[r][0]};                                 \
                v2f x1 = {xr[r][1], xr[r][1]};                                 \
                acc2[r][j2] = fma2(x1, bhi, fma2(x0, blo, acc2[r][j2]));       \
            }                                                                  \
        }                                                                      \
    }

    v2f acc2[8][5];
    #pragma unroll
    for (int r = 0; r < 8; ++r)
        #pragma unroll
        for (int j = 0; j < 5; ++j) acc2[r][j] = (v2f){0.f, 0.f};

    const int NSTEPS = NSUP * 2;        // steps of 128 k
    v2f sv[10], xa[8], xb[8];

    // prologue: stage super 0 into buf0; issue X for steps 0,1
    STAGE_LOAD(sv, kbase);
    STAGE_WRITE(sv, smem);
    LOAD_X(xa, 0);
    LOAD_X(xb, 1);
    __syncthreads();

    #pragma unroll 1
    for (int sup = 0; sup < NSUP; ++sup) {
        const int buf = sup & 1;
        const float* pbase = smem + buf * PANEL_FLOATS;
        if (sup + 1 < NSUP)
            STAGE_LOAD(sv, kbase + (sup + 1) * 256);     // issue early (async)
        // step 2*sup (k offset 0 in panel)
        COMPUTE(xa, pbase);
        if (2 * sup + 2 < NSTEPS) LOAD_X(xa, 2 * sup + 2);   // refill for t+2
        // step 2*sup+1 (k offset 128 -> float offset 256)
        COMPUTE(xb, pbase + 256);
        if (2 * sup + 3 < NSTEPS) LOAD_X(xb, 2 * sup + 3);
        if (sup + 1 < NSUP)
            STAGE_WRITE(sv, smem + (buf ^ 1) * PANEL_FLOATS); // waits its loads
        __syncthreads();
    }
#undef STAGE_LOAD
#undef STAGE_WRITE
#undef LOAD_X
#undef COMPUTE

    // ---- recursive-halving reduce-scatter over 16-lane groups -------------
    // 80 values/lane, flat index i = r*10 + colInCg; ALL accesses are
    // compile-time-constant GEPs on acc2 (stays in VGPRs).
#define V(i) acc2[(i) / 10][((i) % 10) >> 1][(i) & 1]
    {
        const bool u1 = lane & 1;
        #pragma unroll
        for (int i = 0; i < 40; ++i) {
            float snd = u1 ? V(i) : V(i + 40);
            float rcv = __shfl_xor(snd, 1, 64);
            V(i) = (u1 ? V(i + 40) : V(i)) + rcv;
        }
        const bool u2 = lane & 2;
        #pragma unroll
        for (int i = 0; i < 20; ++i) {
            float snd = u2 ? V(i) : V(i + 20);
            float rcv = __shfl_xor(snd, 2, 64);
            V(i) = (u2 ? V(i + 20) : V(i)) + rcv;
        }
        const bool u4 = lane & 4;
        #pragma unroll
        for (int i = 0; i < 10; ++i) {
            float snd = u4 ? V(i) : V(i + 10);
            float rcv = __shfl_xor(snd, 4, 64);
            V(i) = (u4 ? V(i + 10) : V(i)) + rcv;
        }
        const bool u8 = lane & 8;
        #pragma unroll
        for (int i = 0; i < 5; ++i) {
            float snd = u8 ? V(i) : V(i + 5);
            float rcv = __shfl_xor(snd, 8, 64);
            V(i) = (u8 ? V(i + 5) : V(i)) + rcv;
        }
    }
    // lane holds flat indices base..base+4, base = 40a+20b+10c+5d (lane bits)
    {
        const int a = lane & 1, b = (lane >> 1) & 1;
        const int c = (lane >> 2) & 1, d = (lane >> 3) & 1;
        const int g  = lane >> 4;                   // partial group 0..3
        const int r0 = 4 * a + 2 * b + c;           // row within row-group
        const int c0 = cg * 10 + 5 * d;             // first col
        #pragma unroll
        for (int t = 0; t < 5; ++t)
            smem[(rg * 8 + r0) * HROW + (c0 + t) * 4 + g] = V(t);
    }
#undef V
    __syncthreads();

    if (tid < 16) {
        float l[40];
        #pragma unroll
        for (int cc = 0; cc < 40; ++cc) {
            v4f q = *(const v4f*)(smem + tid * HROW + cc * 4);
            l[cc] = (q[0] + q[1]) + (q[2] + q[3]);
        }
        if (FUSED) {
            #pragma unroll
            for (int cc = 0; cc < 40; ++cc) l[cc] += bias2[cc];
            float mC = l[0];
            #pragma unroll
            for (int cc = 1; cc < 20; ++cc) mC = fmaxf(mC, l[cc]);
            float e[20];
            float sC = 0.f;
            #pragma unroll
            for (int cc = 0; cc < 20; ++cc) { e[cc] = expf(l[cc] - mC); sC += e[cc]; }
            float mF = l[20], mnF = l[20];
            #pragma unroll
            for (int cc = 21; cc < 40; ++cc) {
                mF = fmaxf(mF, l[cc]);
                mnF = fminf(mnF, l[cc]);
            }
            float sF = 0.f;
            #pragma unroll
            for (int cc = 20; cc < 40; ++cc) sF += expf(l[cc] - mF);
            float pred  = 1.f / sC;                 // max softmax == exp(0)/sum
            float tau   = expf(mnF - mF) / sF;      // min softmax of flow head
            float scale = (pred >= tau + SMARG) ? pred : 0.f;
            float* op = outp + (size_t)(m0 + tid) * NCLS;
            #pragma unroll
            for (int j = 0; j < 5; ++j) {
                v4f o;
                #pragma unroll
                for (int i = 0; i < 4; ++i) o[i] = e[4 * j + i] * scale;
                *(v4f*)(op + 4 * j) = o;
            }
        } else {
            #pragma unroll
            for (int cc = 0; cc < 40; ++cc)
                atomicAdd(Cacc + (size_t)(m0 + tid) * 40 + cc, l[cc]);
        }
    }
}

extern "C" void kernel_launch(void* const* d_in, const int* in_sizes, int n_in,
                              void* d_out, int out_size, void* d_ws, size_t ws_size,
                              hipStream_t stream) {
    const float* X  = (const float*)d_in[0];
    const float* We = (const float*)d_in[1];
    const float* be = (const float*)d_in[2];
    const float* Wc = (const float*)d_in[3];
    const float* bc = (const float*)d_in[4];
    const float* Wf = (const float*)d_in[5];
    const float* bf = (const float*)d_in[6];
    float* out = (float*)d_out;
    float* ws  = (float*)d_ws;
    (void)in_sizes; (void)n_in; (void)out_size; (void)ws_size;

    // K0: zero Weff + fold bias2
    k0_prep<<<dim3(120), dim3(256), 0, stream>>>(Wc, bc, Wf, bf, be, ws);
    // K1: Weff = We @ [Wc|Wf]  (128 row-blocks x 4 block-K splits = 512 blocks)
    panel_gemm<2, false><<<dim3(512), dim3(512), 0, stream>>>(
        We, Wc, Wf, ws + WEFF_OFF, nullptr, nullptr);
    // K2: out = softmax-threshold(X @ Weff + bias2)  (1024 blocks x 16 rows)
    panel_gemm<8, true><<<dim3(1024), dim3(512), 0, stream>>>(
        X, ws + WEFF_OFF, nullptr, nullptr, ws + BIAS_OFF, out);
}